// Round 1
// baseline (251.519 us; speedup 1.0000x reference)
//
#include <hip/hip_runtime.h>

#define NEL 1024
#define NUP 512
#define DEMB 256
#define WID 64

// LDS layout offsets (floats) per weight set
#define OFF_W0  0      // 4*64, row-major [k][n]
#define OFF_B0  256    // 64
#define OFF_W1T 320    // 64*64 TRANSPOSED: [n][k] so inner k-loop is contiguous
#define OFF_B1  4416   // 64
#define OFF_W2  4480   // 64
#define SET_SIZE 4544

__device__ __forceinline__ float fast_tanh(float x) {
    // tanh(x) = 1 - 2/(exp(2x)+1); exact at +-inf, NaN-free for finite x
    float e = __expf(2.0f * x);
    return 1.0f - __fdividef(2.0f, e + 1.0f);
}

__device__ __forceinline__ float softplus_f(float x) {
    return fmaxf(x, 0.0f) + __logf(1.0f + __expf(-fabsf(x)));
}

__global__ __launch_bounds__(256, 2) void pair_kernel(
    const float* __restrict__ electrons,
    const float* __restrict__ A_same_p, const float* __restrict__ A_diff_p,
    const float* __restrict__ W0s, const float* __restrict__ b0s,
    const float* __restrict__ W1s, const float* __restrict__ b1s,
    const float* __restrict__ W2s,
    const float* __restrict__ W0d, const float* __restrict__ b0d,
    const float* __restrict__ W1d, const float* __restrict__ b1d,
    const float* __restrict__ W2d,
    const float* __restrict__ scale_s_p, const float* __restrict__ scale_d_p,
    float* __restrict__ accum)
{
    __shared__ float lds[2 * SET_SIZE];
    __shared__ float wsum[4];
    const int tid = threadIdx.x;

    // Stage both weight sets into LDS; W1 transposed.
    for (int idx = tid; idx < SET_SIZE; idx += 256) {
        float vs, vd;
        if (idx < OFF_B0)        { vs = W0s[idx];            vd = W0d[idx]; }
        else if (idx < OFF_W1T)  { int q = idx - OFF_B0;     vs = b0s[q];   vd = b0d[q]; }
        else if (idx < OFF_B1)   { int q = idx - OFF_W1T; int n = q >> 6, k = q & 63;
                                   vs = W1s[k*64 + n];       vd = W1d[k*64 + n]; }
        else if (idx < OFF_W2)   { int q = idx - OFF_B1;     vs = b1s[q];   vd = b1d[q]; }
        else                     { int q = idx - OFF_W2;     vs = W2s[q];   vd = W2d[q]; }
        lds[idx] = vs;
        lds[SET_SIZE + idx] = vd;
    }
    __syncthreads();

    const int t = blockIdx.x * 256 + tid;
    const int i = t >> 10;
    const int j = t & 1023;

    float contrib = 0.0f;
    if (i != j) {
        const bool same = (i < NUP) == (j < NUP);
        const float A_raw = same ? A_same_p[0] : A_diff_p[0];
        const float A = softplus_f(A_raw);
        const float invF = rsqrtf(2.0f * A);           // 1/sqrt(2A)
        const float scl = same ? scale_s_p[0] : scale_d_p[0];
        const float* Wb = same ? lds : (lds + SET_SIZE);

        const float dx = electrons[3*i+0] - electrons[3*j+0];
        const float dy = electrons[3*i+1] - electrons[3*j+1];
        const float dz = electrons[3*i+2] - electrons[3*j+2];
        const float r2 = dx*dx + dy*dy + dz*dz;
        const float r = sqrtf(r2);
        const float inv_r = __fdividef(1.0f, r);

        // cusp: A * expm1(-r/F)/r
        const float cusp = A * (__expf(-r * invF) - 1.0f) * inv_r;

        // features [dx*g, dy*g, dz*g, log1p(r)] with g = log1p(r)/r
        const float l1p = __logf(1.0f + r);
        const float g = l1p * inv_r;
        const float f0 = dx * g, f1 = dy * g, f2 = dz * g, f3 = l1p;

        // layer 1: 4 -> 64
        float h0[WID];
        #pragma unroll
        for (int n = 0; n < WID; ++n) {
            float a = Wb[OFF_B0 + n];
            a = fmaf(f0, Wb[OFF_W0 +       n], a);
            a = fmaf(f1, Wb[OFF_W0 +  64 + n], a);
            a = fmaf(f2, Wb[OFF_W0 + 128 + n], a);
            a = fmaf(f3, Wb[OFF_W0 + 192 + n], a);
            h0[n] = fast_tanh(a);
        }

        // layer 2 (64->64) fused with layer 3 (64->1)
        float out = 0.0f;
        #pragma unroll 2
        for (int n = 0; n < WID; ++n) {
            float a = Wb[OFF_B1 + n];
            const float* w1 = &Wb[OFF_W1T + n * 64];
            #pragma unroll
            for (int k = 0; k < WID; ++k)
                a = fmaf(h0[k], w1[k], a);
            out = fmaf(fast_tanh(a), Wb[OFF_W2 + n], out);
        }
        contrib = cusp + scl * out;
    }

    // wave reduce (64 lanes)
    #pragma unroll
    for (int off = 32; off > 0; off >>= 1)
        contrib += __shfl_down(contrib, off);
    const int wave = tid >> 6;
    if ((tid & 63) == 0) wsum[wave] = contrib;
    __syncthreads();
    if (tid == 0)
        atomicAdd(accum, wsum[0] + wsum[1] + wsum[2] + wsum[3]);
}

__global__ __launch_bounds__(64) void embed_kernel(
    const float* __restrict__ emb,
    const float* __restrict__ We0, const float* __restrict__ be0,
    const float* __restrict__ We1, const float* __restrict__ be1,
    const float* __restrict__ We2, const float* __restrict__ be2,
    const float* __restrict__ mlp_scale, const float* __restrict__ log_bias,
    float* __restrict__ accum)
{
    __shared__ float xs[DEMB];
    __shared__ float h0s[WID];
    const int lane = threadIdx.x;
    const int row = blockIdx.x;

    #pragma unroll
    for (int k = lane; k < DEMB; k += 64) xs[k] = emb[row * DEMB + k];
    __syncthreads();

    float a = be0[lane];
    for (int k = 0; k < DEMB; ++k) a = fmaf(xs[k], We0[k * WID + lane], a);
    h0s[lane] = fast_tanh(a);
    __syncthreads();

    float a1 = be1[lane];
    #pragma unroll
    for (int k = 0; k < WID; ++k) a1 = fmaf(h0s[k], We1[k * WID + lane], a1);
    const float h1 = fast_tanh(a1);

    float p0 = h1 * We2[lane * 2 + 0];
    float p1 = h1 * We2[lane * 2 + 1];
    #pragma unroll
    for (int off = 32; off > 0; off >>= 1) {
        p0 += __shfl_down(p0, off);
        p1 += __shfl_down(p1, off);
    }
    if (lane == 0) {
        const float J0 = (p0 + be2[0]) * mlp_scale[0];
        const float J1 = (p1 + be2[1]) * mlp_scale[1] + log_bias[0];
        atomicAdd(&accum[1], J0);
        atomicAdd(&accum[2], J1);
    }
}

__global__ void final_kernel(const float* __restrict__ accum, float* __restrict__ out)
{
    const float s  = accum[0];
    const float J0 = accum[1];
    const float J1 = accum[2];
    const float sign = (J1 > 0.0f) ? 1.0f : ((J1 < 0.0f) ? -1.0f : 0.0f);
    out[0] = sign;
    out[1] = s + J0 + __logf(fabsf(J1));
}

extern "C" void kernel_launch(void* const* d_in, const int* in_sizes, int n_in,
                              void* d_out, int out_size, void* d_ws, size_t ws_size,
                              hipStream_t stream) {
    const float* electrons  = (const float*)d_in[0];
    const float* embeddings = (const float*)d_in[1];
    const float* A_same     = (const float*)d_in[2];
    const float* A_diff     = (const float*)d_in[3];
    const float* Ws0_same   = (const float*)d_in[4];
    const float* bs0_same   = (const float*)d_in[5];
    const float* Ws1_same   = (const float*)d_in[6];
    const float* bs1_same   = (const float*)d_in[7];
    const float* Ws2_same   = (const float*)d_in[8];
    const float* Ws0_diff   = (const float*)d_in[9];
    const float* bs0_diff   = (const float*)d_in[10];
    const float* Ws1_diff   = (const float*)d_in[11];
    const float* bs1_diff   = (const float*)d_in[12];
    const float* Ws2_diff   = (const float*)d_in[13];
    const float* scale_same = (const float*)d_in[14];
    const float* scale_diff = (const float*)d_in[15];
    const float* We0        = (const float*)d_in[16];
    const float* be0        = (const float*)d_in[17];
    const float* We1        = (const float*)d_in[18];
    const float* be1        = (const float*)d_in[19];
    const float* We2        = (const float*)d_in[20];
    const float* be2        = (const float*)d_in[21];
    const float* mlp_scale  = (const float*)d_in[22];
    const float* log_bias   = (const float*)d_in[23];

    float* out   = (float*)d_out;
    float* accum = (float*)d_ws;

    hipMemsetAsync(accum, 0, 4 * sizeof(float), stream);

    hipLaunchKernelGGL(pair_kernel, dim3((NEL * NEL) / 256), dim3(256), 0, stream,
        electrons, A_same, A_diff,
        Ws0_same, bs0_same, Ws1_same, bs1_same, Ws2_same,
        Ws0_diff, bs0_diff, Ws1_diff, bs1_diff, Ws2_diff,
        scale_same, scale_diff, accum);

    hipLaunchKernelGGL(embed_kernel, dim3(NEL), dim3(64), 0, stream,
        embeddings, We0, be0, We1, be1, We2, be2, mlp_scale, log_bias, accum);

    hipLaunchKernelGGL(final_kernel, dim3(1), dim3(1), 0, stream, accum, out);
}

// Round 2
// 99.081 us; speedup vs baseline: 2.5385x; 2.5385x over previous
//
#include <hip/hip_runtime.h>

#define NEL 1024
#define NUP 512
#define DEMB 256
#define WID 64

typedef __attribute__((ext_vector_type(8))) short bf16x8;
typedef __attribute__((ext_vector_type(4))) float f32x4;

#define CTANH 2.8853900817779268f   // 2*log2(e): prescale so tanh(a)=1-2/(exp2(y)+1), y=CTANH*a
#define LOG2E 1.4426950408889634f
#define LN2   0.6931471805599453f

__device__ __forceinline__ float tanh_pre(float y) {
    // y = 2*log2(e)*a ; returns tanh(a). Exact at +-inf, NaN-free for finite y.
    float e = __builtin_amdgcn_exp2f(y);
    return 1.0f - 2.0f * __builtin_amdgcn_rcpf(e + 1.0f);
}

__device__ __forceinline__ short f2bf(float x) {
    // round-to-nearest-even f32 -> bf16 bits (no NaN inputs by construction)
    unsigned u = __builtin_bit_cast(unsigned, x);
    u += 0x7FFFu + ((u >> 16) & 1u);
    return (short)(u >> 16);
}

__device__ __forceinline__ float softplus_f(float x) {
    return fmaxf(x, 0.0f) + __logf(1.0f + __expf(-fabsf(x)));
}

// LDS layout: w1t[c][k] bf16, row stride 72 (144B -> conflict-free b128 frag reads)
//             w0t4: 4 replicated copies of W0^T, copy stride 260 floats (1040B)
__global__ __launch_bounds__(256, 2) void pair_kernel(
    const float* __restrict__ electrons,
    const float* __restrict__ A_same_p, const float* __restrict__ A_diff_p,
    const float* __restrict__ W0s, const float* __restrict__ b0s_g,
    const float* __restrict__ W1s, const float* __restrict__ b1s_g,
    const float* __restrict__ W2s,
    const float* __restrict__ W0d, const float* __restrict__ b0d_g,
    const float* __restrict__ W1d, const float* __restrict__ b1d_g,
    const float* __restrict__ W2d,
    const float* __restrict__ scale_s_p, const float* __restrict__ scale_d_p,
    float* __restrict__ accum)
{
    __shared__ __align__(16) short w1t[64 * 72];
    __shared__ __align__(16) float w0t4[4 * 260];
    __shared__ float b0sh[64], b1sh[64], w2sh[64];
    __shared__ float wsum[4];

    const int tid  = threadIdx.x;
    const int bidx = blockIdx.x;
    const int i        = bidx >> 4;          // 16 blocks per i-row
    const int jb_block = (bidx & 15) << 6;   // 64 j's per block
    const bool same = (i < NUP) == (jb_block < NUP);

    const float* W0 = same ? W0s : W0d;
    const float* B0 = same ? b0s_g : b0d_g;
    const float* W1 = same ? W1s : W1d;
    const float* B1 = same ? b1s_g : b1d_g;
    const float* W2 = same ? W2s : W2d;

    // ---- stage weights (one spin set per block; block is spin-uniform) ----
    #pragma unroll
    for (int it = 0; it < 16; ++it) {
        int idx = tid + it * 256;            // idx = k*64 + c
        int k = idx >> 6, c = idx & 63;
        w1t[c * 72 + k] = f2bf(CTANH * W1[idx]);
    }
    {
        int k = tid >> 6, n = tid & 63;      // W0 is (4,64) row-major
        float v = CTANH * W0[tid];
        #pragma unroll
        for (int b = 0; b < 4; ++b) w0t4[b * 260 + n * 4 + k] = v;
    }
    if (tid < 64) {
        b0sh[tid] = CTANH * B0[tid];
        b1sh[tid] = CTANH * B1[tid];
        w2sh[tid] = W2[tid];
    }
    __syncthreads();

    const int lane = tid & 63;
    const int wv   = tid >> 6;
    const int g    = lane >> 4;     // k-block group for A/B fragments
    const int c16  = lane & 15;
    const int jbase = jb_block + (wv << 4);
    const int j     = jbase + c16;
    const int diag_p = i - jbase;   // in [0,16) iff this wave contains the diagonal
    const bool is_diag = (c16 == diag_p);

    // per-pair-type scalars (wave-uniform)
    const float A_raw = same ? A_same_p[0] : A_diff_p[0];
    const float A     = softplus_f(A_raw);
    const float invF2 = __builtin_amdgcn_rsqf(2.0f * A) * LOG2E;  // log2(e)/F
    const float scl   = same ? scale_s_p[0] : scale_d_p[0];

    // ---- features ----
    const float eix = electrons[3 * i], eiy = electrons[3 * i + 1], eiz = electrons[3 * i + 2];
    float dx = eix - electrons[3 * j];
    float dy = eiy - electrons[3 * j + 1];
    float dz = eiz - electrons[3 * j + 2];
    if (is_diag) { dx = 0.0f; dy = 0.0f; dz = 0.0f; }
    float r2 = fmaf(dx, dx, fmaf(dy, dy, dz * dz));
    if (is_diag) r2 = 1.0f;                       // sanitize: no inf/NaN anywhere
    const float rr    = __builtin_amdgcn_sqrtf(r2);
    const float inv_r = __builtin_amdgcn_rcpf(rr);
    const float l1p   = __builtin_amdgcn_logf(1.0f + rr) * LN2;
    const float gf    = l1p * inv_r;
    const float f0 = dx * gf, f1 = dy * gf, f2 = dz * gf;
    const float f3 = is_diag ? 0.0f : l1p;

    float cusp = 0.0f;
    if (g == 0 && !is_diag)
        cusp = A * (__builtin_amdgcn_exp2f(-rr * invF2) - 1.0f) * inv_r;

    // ---- layer 1 (VALU) directly into A-fragment layout ----
    // lane computes h0 for pair c16, neurons n = 8g+e (frag a0) and 32+8g+e (frag a1)
    bf16x8 a0, a1;
    const int nb = g << 3;
    const float* w0base = &w0t4[g * 260];
    #pragma unroll
    for (int e = 0; e < 8; ++e) {
        const int n0 = nb + e;
        const int n1 = 32 + nb + e;
        f32x4 w = *(const f32x4*)(w0base + 4 * n0);
        float y0 = fmaf(f3, w[3], fmaf(f2, w[2], fmaf(f1, w[1], fmaf(f0, w[0], b0sh[n0]))));
        f32x4 v = *(const f32x4*)(w0base + 4 * n1);
        float y1 = fmaf(f3, v[3], fmaf(f2, v[2], fmaf(f1, v[1], fmaf(f0, v[0], b0sh[n1]))));
        a0[e] = f2bf(tanh_pre(y0));
        a1[e] = f2bf(tanh_pre(y1));
    }

    // ---- layer 2 (MFMA) + layer 3 fused epilogue ----
    float s_acc = 0.0f;
    #pragma unroll
    for (int t = 0; t < 4; ++t) {
        const int c = (t << 4) + c16;
        bf16x8 bf0 = *(const bf16x8*)&w1t[c * 72 + (g << 3)];
        bf16x8 bf1 = *(const bf16x8*)&w1t[c * 72 + 32 + (g << 3)];
        const float bb = b1sh[c];
        f32x4 acc; acc[0] = bb; acc[1] = bb; acc[2] = bb; acc[3] = bb;
        acc = __builtin_amdgcn_mfma_f32_16x16x32_bf16(a0, bf0, acc, 0, 0, 0);
        acc = __builtin_amdgcn_mfma_f32_16x16x32_bf16(a1, bf1, acc, 0, 0, 0);
        const float w2v = w2sh[c];
        #pragma unroll
        for (int r = 0; r < 4; ++r) {
            const int p = (g << 2) + r;               // pair index (C/D row map)
            float t2 = tanh_pre(acc[r]);
            s_acc += (p == diag_p) ? 0.0f : t2 * w2v;
        }
    }
    float partial = fmaf(s_acc, scl, cusp);

    // ---- reduce: wave -> block -> 64 spread atomic buckets ----
    #pragma unroll
    for (int off = 32; off; off >>= 1) partial += __shfl_down(partial, off);
    if (lane == 0) wsum[wv] = partial;
    __syncthreads();
    if (tid == 0)
        atomicAdd(&accum[(bidx & 63) << 4], wsum[0] + wsum[1] + wsum[2] + wsum[3]);
}

__global__ __launch_bounds__(64) void embed_kernel(
    const float* __restrict__ emb,
    const float* __restrict__ We0, const float* __restrict__ be0,
    const float* __restrict__ We1, const float* __restrict__ be1,
    const float* __restrict__ We2, const float* __restrict__ be2,
    const float* __restrict__ mlp_scale, const float* __restrict__ log_bias,
    float* __restrict__ accum)
{
    __shared__ float xs[DEMB];
    __shared__ float h0s[WID];
    const int lane = threadIdx.x;
    const int row = blockIdx.x;

    #pragma unroll
    for (int k = lane; k < DEMB; k += 64) xs[k] = emb[row * DEMB + k];
    __syncthreads();

    float a = be0[lane];
    for (int k = 0; k < DEMB; ++k) a = fmaf(xs[k], We0[k * WID + lane], a);
    h0s[lane] = tanh_pre(CTANH * a);
    __syncthreads();

    float a1 = be1[lane];
    #pragma unroll
    for (int k = 0; k < WID; ++k) a1 = fmaf(h0s[k], We1[k * WID + lane], a1);
    const float h1 = tanh_pre(CTANH * a1);

    float p0 = h1 * We2[lane * 2 + 0];
    float p1 = h1 * We2[lane * 2 + 1];
    #pragma unroll
    for (int off = 32; off > 0; off >>= 1) {
        p0 += __shfl_down(p0, off);
        p1 += __shfl_down(p1, off);
    }
    if (lane == 0) {
        const float J0 = (p0 + be2[0]) * mlp_scale[0];
        const float J1 = (p1 + be2[1]) * mlp_scale[1] + log_bias[0];
        atomicAdd(&accum[1024], J0);
        atomicAdd(&accum[1025], J1);
    }
}

__global__ __launch_bounds__(64) void final_kernel(const float* __restrict__ accum,
                                                   float* __restrict__ out)
{
    const int lane = threadIdx.x;
    float v = accum[lane << 4];
    #pragma unroll
    for (int off = 32; off; off >>= 1) v += __shfl_down(v, off);
    if (lane == 0) {
        const float J0 = accum[1024];
        const float J1 = accum[1025];
        const float sign = (J1 > 0.0f) ? 1.0f : ((J1 < 0.0f) ? -1.0f : 0.0f);
        out[0] = sign;
        out[1] = v + J0 + logf(fabsf(J1));
    }
}

extern "C" void kernel_launch(void* const* d_in, const int* in_sizes, int n_in,
                              void* d_out, int out_size, void* d_ws, size_t ws_size,
                              hipStream_t stream) {
    const float* electrons  = (const float*)d_in[0];
    const float* embeddings = (const float*)d_in[1];
    const float* A_same     = (const float*)d_in[2];
    const float* A_diff     = (const float*)d_in[3];
    const float* Ws0_same   = (const float*)d_in[4];
    const float* bs0_same   = (const float*)d_in[5];
    const float* Ws1_same   = (const float*)d_in[6];
    const float* bs1_same   = (const float*)d_in[7];
    const float* Ws2_same   = (const float*)d_in[8];
    const float* Ws0_diff   = (const float*)d_in[9];
    const float* bs0_diff   = (const float*)d_in[10];
    const float* Ws1_diff   = (const float*)d_in[11];
    const float* bs1_diff   = (const float*)d_in[12];
    const float* Ws2_diff   = (const float*)d_in[13];
    const float* scale_same = (const float*)d_in[14];
    const float* scale_diff = (const float*)d_in[15];
    const float* We0        = (const float*)d_in[16];
    const float* be0        = (const float*)d_in[17];
    const float* We1        = (const float*)d_in[18];
    const float* be1        = (const float*)d_in[19];
    const float* We2        = (const float*)d_in[20];
    const float* be2        = (const float*)d_in[21];
    const float* mlp_scale  = (const float*)d_in[22];
    const float* log_bias   = (const float*)d_in[23];

    float* out   = (float*)d_out;
    float* accum = (float*)d_ws;

    hipMemsetAsync(accum, 0, 1026 * sizeof(float), stream);

    hipLaunchKernelGGL(pair_kernel, dim3((NEL * NEL) / 64), dim3(256), 0, stream,
        electrons, A_same, A_diff,
        Ws0_same, bs0_same, Ws1_same, bs1_same, Ws2_same,
        Ws0_diff, bs0_diff, Ws1_diff, bs1_diff, Ws2_diff,
        scale_same, scale_diff, accum);

    hipLaunchKernelGGL(embed_kernel, dim3(NEL), dim3(64), 0, stream,
        embeddings, We0, be0, We1, be1, We2, be2, mlp_scale, log_bias, accum);

    hipLaunchKernelGGL(final_kernel, dim3(1), dim3(64), 0, stream, accum, out);
}

// Round 3
// 89.194 us; speedup vs baseline: 2.8199x; 1.1109x over previous
//
#include <hip/hip_runtime.h>
#include <hip/hip_bf16.h>

#define NEL 1024
#define NUP 512
#define DEMB 256
#define WID 64

typedef __attribute__((ext_vector_type(8))) short bf16x8;
typedef __attribute__((ext_vector_type(4))) float f32x4;
typedef __attribute__((ext_vector_type(16))) float f32x16;

#define CTANH 2.8853900817779268f   // 2*log2(e): tanh(a)=1-2/(exp2(CTANH*a)+1)
#define LOG2E 1.4426950408889634f
#define LN2   0.6931471805599453f

// ws float layout:
//  [0..1023]    : 64 spread accumulation buckets (stride 16)
//  [1024,1025]  : J0, J1
//  [2048+s*1024]: per-set: w0t[256] (W0^T*CTANH, f32x4/neuron), +256 b0p[64],
//                 +320 b1p[64], +384 w2[64], +448 {A, log2e/F, scale}
//  float idx 4096 onward, as shorts: w1t_s[4608], w1t_d[4608]  ([n][72] bf16, *CTANH)

__device__ __forceinline__ float tanh_pre(float y) {
    // y = CTANH * a ; returns tanh(a). Saturates correctly, NaN-free for finite y.
    float e = __builtin_amdgcn_exp2f(y);
    return fmaf(-2.0f, __builtin_amdgcn_rcpf(e + 1.0f), 1.0f);
}

__device__ __forceinline__ short f2bf(float x) {
    unsigned u = __builtin_bit_cast(unsigned, x);
    u += 0x7FFFu + ((u >> 16) & 1u);
    return (short)(u >> 16);
}

__device__ __forceinline__ float softplus_f(float x) {
    return fmaxf(x, 0.0f) + __logf(1.0f + __expf(-fabsf(x)));
}

__global__ __launch_bounds__(256) void prep_kernel(
    const float* __restrict__ W0s, const float* __restrict__ b0s,
    const float* __restrict__ W1s, const float* __restrict__ b1s, const float* __restrict__ W2s,
    const float* __restrict__ W0d, const float* __restrict__ b0d,
    const float* __restrict__ W1d, const float* __restrict__ b1d, const float* __restrict__ W2d,
    const float* __restrict__ As, const float* __restrict__ Ad,
    const float* __restrict__ ss, const float* __restrict__ sd,
    float* __restrict__ wsf)
{
    short* w1ws = (short*)(wsf + 4096);
    const int tid = threadIdx.x;
    #pragma unroll
    for (int s = 0; s < 2; ++s) {
        const float* W1 = s ? W1d : W1s;
        const float* W0 = s ? W0d : W0s;
        const float* b0 = s ? b0d : b0s;
        const float* b1 = s ? b1d : b1s;
        const float* w2 = s ? W2d : W2s;
        for (int idx = tid; idx < 4096; idx += 256) {
            int k = idx >> 6, n = idx & 63;
            w1ws[s * 4608 + n * 72 + k] = f2bf(CTANH * W1[idx]);  // [n][k] = W1^T, prescaled
        }
        const int base = 2048 + s * 1024;
        { int k = tid >> 6, n = tid & 63; wsf[base + n * 4 + k] = CTANH * W0[tid]; }
        if (tid < 64) {
            wsf[base + 256 + tid] = CTANH * b0[tid];
            wsf[base + 320 + tid] = CTANH * b1[tid];
            wsf[base + 384 + tid] = w2[tid];
        }
        if (tid == 0) {
            float A = softplus_f((s ? Ad : As)[0]);
            wsf[base + 448] = A;
            wsf[base + 449] = LOG2E * __builtin_amdgcn_rsqf(2.0f * A);  // log2e / F
            wsf[base + 450] = (s ? sd : ss)[0];
        }
    }
}

// Wave = 32 pairs. Layer2: D[neuron][pair] = W1^T (A) x h0 (B), 32x32x16, 2 n-tiles x 4 k-chunks.
__global__ __launch_bounds__(256, 2) void pair_kernel(
    const float* __restrict__ electrons,
    const float* __restrict__ wsf,
    float* __restrict__ accum)
{
    __shared__ __align__(16) short w1t[4608];   // [n][72] bf16 prescaled
    __shared__ __align__(16) float w0t[256];    // [n][4]  f32 prescaled
    __shared__ float b0sh[64], b1sh[64], w2sh[64];
    __shared__ float wsum[4];

    const int tid  = threadIdx.x;
    const int bidx = blockIdx.x;
    const int i  = bidx >> 3;
    const int jb = (bidx & 7) << 7;            // 128 j per block (spin-uniform)
    const int sset = ((i < NUP) == (jb < NUP)) ? 0 : 1;
    const float* wbase = wsf + 2048 + sset * 1024;
    const short* w1g   = (const short*)(wsf + 4096) + sset * 4608;

    // pure vector-copy staging (preconverted in prep)
    {
        const float4* src = (const float4*)w1g;
        float4* dst = (float4*)w1t;
        for (int idx = tid; idx < 576; idx += 256) dst[idx] = src[idx];
        if (tid < 64) {
            ((float4*)w0t)[tid] = ((const float4*)wbase)[tid];
            b0sh[tid] = wbase[256 + tid];
            b1sh[tid] = wbase[320 + tid];
            w2sh[tid] = wbase[384 + tid];
        }
    }
    const float A     = wbase[448];
    const float invF2 = wbase[449];
    const float scl   = wbase[450];
    __syncthreads();

    const int lane = tid & 63, wv = tid >> 6;
    const int hi = lane >> 5, p32 = lane & 31;
    const int j = jb + (wv << 5) + p32;
    const bool diag = (j == i);

    // ---- features (sanitized on diagonal) ----
    const float eix = electrons[3 * i], eiy = electrons[3 * i + 1], eiz = electrons[3 * i + 2];
    float dx = eix - electrons[3 * j];
    float dy = eiy - electrons[3 * j + 1];
    float dz = eiz - electrons[3 * j + 2];
    if (diag) { dx = 0.0f; dy = 0.0f; dz = 0.0f; }
    float r2 = fmaf(dx, dx, fmaf(dy, dy, dz * dz));
    if (diag) r2 = 1.0f;
    const float rr    = __builtin_amdgcn_sqrtf(r2);
    const float inv_r = __builtin_amdgcn_rcpf(rr);
    const float l1p   = __builtin_amdgcn_logf(1.0f + rr) * LN2;
    const float gf    = l1p * inv_r;
    const float f0 = dx * gf, f1 = dy * gf, f2v = dz * gf;
    const float f3 = diag ? 0.0f : l1p;
    const float cusp = (hi == 0 && !diag)
        ? A * (__builtin_amdgcn_exp2f(-rr * invF2) - 1.0f) * inv_r : 0.0f;

    // ---- layer 1 (VALU) straight into B-fragment layout ----
    // lane owns pair p32; k-elem e of chunk kc = neuron n = 16*kc + 8*hi + e
    bf16x8 afr[4];
    #pragma unroll
    for (int kc = 0; kc < 4; ++kc) {
        #pragma unroll
        for (int e = 0; e < 8; ++e) {
            const int n = (kc << 4) + (hi << 3) + e;
            f32x4 w = *(const f32x4*)&w0t[n << 2];
            float y = fmaf(f3, w[3], fmaf(f2v, w[2], fmaf(f1, w[1], fmaf(f0, w[0], b0sh[n]))));
            afr[kc][e] = __bfloat16_as_ushort(__float2bfloat16(tanh_pre(y)));
        }
    }

    // ---- layer 2 (MFMA 32x32x16), C preloaded with prescaled b1 ----
    f32x16 acc0, acc1;
    #pragma unroll
    for (int r = 0; r < 16; ++r) {
        const int n0 = (r & 3) + ((r >> 2) << 3) + (hi << 2);
        acc0[r] = b1sh[n0];
        acc1[r] = b1sh[32 + n0];
    }
    const short* w1r0 = &w1t[p32 * 72 + (hi << 3)];
    const short* w1r1 = &w1t[(32 + p32) * 72 + (hi << 3)];
    #pragma unroll
    for (int kc = 0; kc < 4; ++kc) {
        bf16x8 wa0 = *(const bf16x8*)(w1r0 + (kc << 4));
        bf16x8 wa1 = *(const bf16x8*)(w1r1 + (kc << 4));
        acc0 = __builtin_amdgcn_mfma_f32_32x32x16_bf16(wa0, afr[kc], acc0, 0, 0, 0);
        acc1 = __builtin_amdgcn_mfma_f32_32x32x16_bf16(wa1, afr[kc], acc1, 0, 0, 0);
    }

    // ---- layer 3 epilogue: lane-local (col = own pair) ----
    float s = 0.0f;
    #pragma unroll
    for (int r = 0; r < 16; ++r) {
        const int n0 = (r & 3) + ((r >> 2) << 3) + (hi << 2);
        s = fmaf(tanh_pre(acc0[r]), w2sh[n0], s);
        s = fmaf(tanh_pre(acc1[r]), w2sh[32 + n0], s);
    }
    if (diag) s = 0.0f;
    float partial = fmaf(s, scl, cusp);   // both hi-halves sum over full 64-lane reduce

    #pragma unroll
    for (int off = 32; off; off >>= 1) partial += __shfl_down(partial, off);
    if (lane == 0) wsum[wv] = partial;
    __syncthreads();
    if (tid == 0)
        atomicAdd(&accum[(bidx & 63) << 4], wsum[0] + wsum[1] + wsum[2] + wsum[3]);
}

__global__ __launch_bounds__(256) void embed_kernel(
    const float* __restrict__ emb,
    const float* __restrict__ We0, const float* __restrict__ be0,
    const float* __restrict__ We1, const float* __restrict__ be1,
    const float* __restrict__ We2, const float* __restrict__ be2,
    const float* __restrict__ mlp_scale, const float* __restrict__ log_bias,
    float* __restrict__ accum)
{
    __shared__ float xs[4][DEMB];
    __shared__ float h0s[4][WID];
    const int tid = threadIdx.x, wv = tid >> 6, lane = tid & 63;
    const int row = (blockIdx.x << 2) + wv;

    for (int k = lane; k < DEMB; k += 64) xs[wv][k] = emb[row * DEMB + k];
    __syncthreads();

    float a0 = 0, a1 = 0, a2 = 0, a3 = 0;
    #pragma unroll 4
    for (int k = 0; k < DEMB; k += 4) {
        a0 = fmaf(xs[wv][k],     We0[(k)     * WID + lane], a0);
        a1 = fmaf(xs[wv][k + 1], We0[(k + 1) * WID + lane], a1);
        a2 = fmaf(xs[wv][k + 2], We0[(k + 2) * WID + lane], a2);
        a3 = fmaf(xs[wv][k + 3], We0[(k + 3) * WID + lane], a3);
    }
    h0s[wv][lane] = tanh_pre(CTANH * ((a0 + a1) + (a2 + a3) + be0[lane]));
    __syncthreads();

    float c0 = 0, c1 = 0;
    #pragma unroll
    for (int k = 0; k < WID; k += 2) {
        c0 = fmaf(h0s[wv][k],     We1[(k)     * WID + lane], c0);
        c1 = fmaf(h0s[wv][k + 1], We1[(k + 1) * WID + lane], c1);
    }
    const float h1 = tanh_pre(CTANH * (c0 + c1 + be1[lane]));

    float p0 = h1 * We2[2 * lane], p1 = h1 * We2[2 * lane + 1];
    #pragma unroll
    for (int off = 32; off; off >>= 1) {
        p0 += __shfl_down(p0, off);
        p1 += __shfl_down(p1, off);
    }
    if (lane == 0) {
        atomicAdd(&accum[1024], (p0 + be2[0]) * mlp_scale[0]);
        atomicAdd(&accum[1025], (p1 + be2[1]) * mlp_scale[1] + log_bias[0]);
    }
}

__global__ __launch_bounds__(64) void final_kernel(const float* __restrict__ accum,
                                                   float* __restrict__ out)
{
    const int lane = threadIdx.x;
    float v = accum[lane << 4];
    #pragma unroll
    for (int off = 32; off; off >>= 1) v += __shfl_down(v, off);
    if (lane == 0) {
        const float J0 = accum[1024];
        const float J1 = accum[1025];
        const float sign = (J1 > 0.0f) ? 1.0f : ((J1 < 0.0f) ? -1.0f : 0.0f);
        out[0] = sign;
        out[1] = v + J0 + logf(fabsf(J1));
    }
}

extern "C" void kernel_launch(void* const* d_in, const int* in_sizes, int n_in,
                              void* d_out, int out_size, void* d_ws, size_t ws_size,
                              hipStream_t stream) {
    const float* electrons  = (const float*)d_in[0];
    const float* embeddings = (const float*)d_in[1];
    const float* A_same     = (const float*)d_in[2];
    const float* A_diff     = (const float*)d_in[3];
    const float* Ws0_same   = (const float*)d_in[4];
    const float* bs0_same   = (const float*)d_in[5];
    const float* Ws1_same   = (const float*)d_in[6];
    const float* bs1_same   = (const float*)d_in[7];
    const float* Ws2_same   = (const float*)d_in[8];
    const float* Ws0_diff   = (const float*)d_in[9];
    const float* bs0_diff   = (const float*)d_in[10];
    const float* Ws1_diff   = (const float*)d_in[11];
    const float* bs1_diff   = (const float*)d_in[12];
    const float* Ws2_diff   = (const float*)d_in[13];
    const float* scale_same = (const float*)d_in[14];
    const float* scale_diff = (const float*)d_in[15];
    const float* We0        = (const float*)d_in[16];
    const float* be0        = (const float*)d_in[17];
    const float* We1        = (const float*)d_in[18];
    const float* be1        = (const float*)d_in[19];
    const float* We2        = (const float*)d_in[20];
    const float* be2        = (const float*)d_in[21];
    const float* mlp_scale  = (const float*)d_in[22];
    const float* log_bias   = (const float*)d_in[23];

    float* out = (float*)d_out;
    float* wsf = (float*)d_ws;

    hipMemsetAsync(wsf, 0, 1026 * sizeof(float), stream);

    hipLaunchKernelGGL(prep_kernel, dim3(1), dim3(256), 0, stream,
        Ws0_same, bs0_same, Ws1_same, bs1_same, Ws2_same,
        Ws0_diff, bs0_diff, Ws1_diff, bs1_diff, Ws2_diff,
        A_same, A_diff, scale_same, scale_diff, wsf);

    hipLaunchKernelGGL(pair_kernel, dim3((NEL * NEL) / 128), dim3(256), 0, stream,
        electrons, wsf, wsf);

    hipLaunchKernelGGL(embed_kernel, dim3(NEL / 4), dim3(256), 0, stream,
        embeddings, We0, be0, We1, be1, We2, be2, mlp_scale, log_bias, wsf);

    hipLaunchKernelGGL(final_kernel, dim3(1), dim3(64), 0, stream, wsf, out);
}

// Round 4
// 81.456 us; speedup vs baseline: 3.0878x; 1.0950x over previous
//
#include <hip/hip_runtime.h>
#include <hip/hip_bf16.h>

#define NEL 1024
#define NUP 512
#define DEMB 256
#define WID 64

typedef __attribute__((ext_vector_type(8))) short bf16x8;
typedef __attribute__((ext_vector_type(4))) float f32x4;
typedef __attribute__((ext_vector_type(16))) float f32x16;

#define CTANH 2.8853900817779268f   // 2*log2(e): tanh(a)=1-2/(exp2(CTANH*a)+1)
#define LOG2E 1.4426950408889634f
#define LN2   0.6931471805599453f

// ws float layout:
//  [0..1023]    : 64 spread accumulation buckets (stride 16)
//  [1024,1025]  : J0, J1
//  [2048+s*1024]: per-set: w0t[256] (W0^T*CTANH), +256 b0p[64]*CTANH,
//                 +320 b1p[64]*CTANH, +384 w2p[64]*scale, +448 {A, log2e/F}
//  float idx 4096 onward, as shorts: w1t_s[4608], w1t_d[4608]  ([n][72] bf16, *CTANH)

__device__ __forceinline__ float tanh_pre(float y) {
    // y = CTANH * a ; returns tanh(a). Saturates correctly, NaN-free for finite y.
    float e = __builtin_amdgcn_exp2f(y);
    return fmaf(-2.0f, __builtin_amdgcn_rcpf(e + 1.0f), 1.0f);
}

__device__ __forceinline__ short f2bf(float x) {
    unsigned u = __builtin_bit_cast(unsigned, x);
    u += 0x7FFFu + ((u >> 16) & 1u);
    return (short)(u >> 16);
}

__device__ __forceinline__ float softplus_f(float x) {
    return fmaxf(x, 0.0f) + __logf(1.0f + __expf(-fabsf(x)));
}

__global__ __launch_bounds__(256) void prep_kernel(
    const float* __restrict__ W0s, const float* __restrict__ b0s,
    const float* __restrict__ W1s, const float* __restrict__ b1s, const float* __restrict__ W2s,
    const float* __restrict__ W0d, const float* __restrict__ b0d,
    const float* __restrict__ W1d, const float* __restrict__ b1d, const float* __restrict__ W2d,
    const float* __restrict__ As, const float* __restrict__ Ad,
    const float* __restrict__ ss, const float* __restrict__ sd,
    float* __restrict__ wsf)
{
    short* w1ws = (short*)(wsf + 4096);
    const int b = blockIdx.x, tid = threadIdx.x;
    if (b < 16) {
        const int s = b >> 3, c = b & 7;
        const float* W1 = s ? W1d : W1s;
        #pragma unroll
        for (int it = 0; it < 2; ++it) {
            const int local = (c << 9) + (it << 8) + tid;   // 512 entries per block
            const int n = local >> 6, k = local & 63;
            w1ws[s * 4608 + n * 72 + k] = f2bf(CTANH * W1[k * 64 + n]);
        }
    } else {
        for (int idx = tid; idx < 1026; idx += 256) wsf[idx] = 0.0f;
        #pragma unroll
        for (int s = 0; s < 2; ++s) {
            const float* W0 = s ? W0d : W0s;
            const float* b0 = s ? b0d : b0s;
            const float* b1 = s ? b1d : b1s;
            const float* w2 = s ? W2d : W2s;
            const float scl = (s ? sd : ss)[0];
            const int base = 2048 + s * 1024;
            { const int k = tid >> 6, n = tid & 63; wsf[base + n * 4 + k] = CTANH * W0[tid]; }
            if (tid < 64) {
                wsf[base + 256 + tid] = CTANH * b0[tid];
                wsf[base + 320 + tid] = CTANH * b1[tid];
                wsf[base + 384 + tid] = scl * w2[tid];
            }
            if (tid == 0) {
                const float A = softplus_f((s ? Ad : As)[0]);
                wsf[base + 448] = A;
                wsf[base + 449] = LOG2E * __builtin_amdgcn_rsqf(2.0f * A);  // log2e/F
            }
        }
    }
}

// Blocks [0,8192): 128 pairs each (wave = 32 pairs, MFMA 32x32x16).
// Blocks [8192,8448): embedding MLP, 4 rows per block.
__global__ __launch_bounds__(256) void pair_kernel(
    const float* __restrict__ electrons,
    const float* __restrict__ wsf,
    float* __restrict__ accum,
    const float* __restrict__ emb,
    const float* __restrict__ We0, const float* __restrict__ be0,
    const float* __restrict__ We1, const float* __restrict__ be1,
    const float* __restrict__ We2, const float* __restrict__ be2,
    const float* __restrict__ mlp_scale, const float* __restrict__ log_bias)
{
    __shared__ __align__(16) char smem[11264];
    const int tid = threadIdx.x, bidx = blockIdx.x;
    const int lane = tid & 63, wv = tid >> 6;

    if (bidx >= 8192) {
        // ---------------- embedding path ----------------
        float* xs  = (float*)smem;          // [4][256]
        float* h0s = (float*)(smem + 4096); // [4][64]
        const int row = ((bidx - 8192) << 2) + wv;

        for (int k = lane; k < DEMB; k += 64) xs[(wv << 8) + k] = emb[row * DEMB + k];
        __syncthreads();

        float a0 = 0, a1 = 0, a2 = 0, a3 = 0;
        #pragma unroll 4
        for (int k = 0; k < DEMB; k += 4) {
            a0 = fmaf(xs[(wv << 8) + k],     We0[(k)     * WID + lane], a0);
            a1 = fmaf(xs[(wv << 8) + k + 1], We0[(k + 1) * WID + lane], a1);
            a2 = fmaf(xs[(wv << 8) + k + 2], We0[(k + 2) * WID + lane], a2);
            a3 = fmaf(xs[(wv << 8) + k + 3], We0[(k + 3) * WID + lane], a3);
        }
        h0s[(wv << 6) + lane] = tanh_pre(CTANH * ((a0 + a1) + (a2 + a3) + be0[lane]));
        __syncthreads();

        float c0 = 0, c1 = 0;
        #pragma unroll
        for (int k = 0; k < WID; k += 2) {
            c0 = fmaf(h0s[(wv << 6) + k],     We1[(k)     * WID + lane], c0);
            c1 = fmaf(h0s[(wv << 6) + k + 1], We1[(k + 1) * WID + lane], c1);
        }
        const float h1 = tanh_pre(CTANH * (c0 + c1 + be1[lane]));

        float p0 = h1 * We2[2 * lane], p1 = h1 * We2[2 * lane + 1];
        #pragma unroll
        for (int off = 32; off; off >>= 1) {
            p0 += __shfl_down(p0, off);
            p1 += __shfl_down(p1, off);
        }
        if (lane == 0) {
            atomicAdd(&accum[1024], (p0 + be2[0]) * mlp_scale[0]);
            atomicAdd(&accum[1025], (p1 + be2[1]) * mlp_scale[1] + log_bias[0]);
        }
        return;
    }

    // ---------------- pair path ----------------
    short* w1t  = (short*)smem;            // [64][72] bf16, prescaled
    float* w0t  = (float*)(smem + 9216);   // [64][4]  f32, prescaled
    float* b0sh = (float*)(smem + 10240);  // [64]
    float* b1sh = (float*)(smem + 10496);  // [64]
    float* w2sh = (float*)(smem + 10752);  // [64] (pre-multiplied by scale)

    const int i  = bidx >> 3;
    const int jb = (bidx & 7) << 7;        // 128 j per block (spin-uniform)
    const int sset = ((i < NUP) == (jb < NUP)) ? 0 : 1;
    const float* wbase = wsf + 2048 + sset * 1024;
    const short* w1g   = (const short*)(wsf + 4096) + sset * 4608;

    {
        const float4* src = (const float4*)w1g;
        float4* dst = (float4*)w1t;
        for (int idx = tid; idx < 576; idx += 256) dst[idx] = src[idx];
        if (tid < 64) {
            ((float4*)w0t)[tid] = ((const float4*)wbase)[tid];
            b0sh[tid] = wbase[256 + tid];
            b1sh[tid] = wbase[320 + tid];
            w2sh[tid] = wbase[384 + tid];
        }
    }
    const float A     = wbase[448];
    const float invF2 = wbase[449];

    const int hi = lane >> 5, p32 = lane & 31;
    const int j = jb + (wv << 5) + p32;
    const bool diag = (j == i);

    // features (loads don't depend on LDS; issue before the barrier)
    const float eix = electrons[3 * i], eiy = electrons[3 * i + 1], eiz = electrons[3 * i + 2];
    float dx = eix - electrons[3 * j];
    float dy = eiy - electrons[3 * j + 1];
    float dz = eiz - electrons[3 * j + 2];
    if (diag) { dx = 0.0f; dy = 0.0f; dz = 0.0f; }
    float r2 = fmaf(dx, dx, fmaf(dy, dy, dz * dz));
    if (diag) r2 = 1.0f;
    const float rr    = __builtin_amdgcn_sqrtf(r2);
    const float inv_r = __builtin_amdgcn_rcpf(rr);
    const float l1p   = __builtin_amdgcn_logf(1.0f + rr) * LN2;
    const float gf    = l1p * inv_r;
    const float f0 = dx * gf, f1 = dy * gf, f2v = dz * gf;
    const float f3 = diag ? 0.0f : l1p;
    const float cusp = (hi == 0 && !diag)
        ? A * (__builtin_amdgcn_exp2f(-rr * invF2) - 1.0f) * inv_r : 0.0f;

    __syncthreads();

    // layer 1 (VALU) straight into B-fragment layout:
    // lane owns pair p32; k-elem e of chunk kc = neuron n = 16*kc + 8*hi + e
    bf16x8 afr[4];
    #pragma unroll
    for (int kc = 0; kc < 4; ++kc) {
        #pragma unroll
        for (int e = 0; e < 8; ++e) {
            const int n = (kc << 4) + (hi << 3) + e;
            f32x4 w = *(const f32x4*)&w0t[n << 2];
            float y = fmaf(f3, w[3], fmaf(f2v, w[2], fmaf(f1, w[1], fmaf(f0, w[0], b0sh[n]))));
            afr[kc][e] = __bfloat16_as_ushort(__float2bfloat16(tanh_pre(y)));
        }
    }

    // layer 2 (MFMA 32x32x16), C preloaded with prescaled b1 via broadcast b128 reads
    f32x16 acc0, acc1;
    #pragma unroll
    for (int q = 0; q < 4; ++q) {
        const f32x4 v0 = *(const f32x4*)&b1sh[(q << 3) + (hi << 2)];
        const f32x4 v1 = *(const f32x4*)&b1sh[32 + (q << 3) + (hi << 2)];
        #pragma unroll
        for (int e = 0; e < 4; ++e) { acc0[(q << 2) + e] = v0[e]; acc1[(q << 2) + e] = v1[e]; }
    }
    const short* w1r0 = &w1t[p32 * 72 + (hi << 3)];
    const short* w1r1 = &w1t[(32 + p32) * 72 + (hi << 3)];
    #pragma unroll
    for (int kc = 0; kc < 4; ++kc) {
        bf16x8 wa0 = *(const bf16x8*)(w1r0 + (kc << 4));
        bf16x8 wa1 = *(const bf16x8*)(w1r1 + (kc << 4));
        acc0 = __builtin_amdgcn_mfma_f32_32x32x16_bf16(wa0, afr[kc], acc0, 0, 0, 0);
        acc1 = __builtin_amdgcn_mfma_f32_32x32x16_bf16(wa1, afr[kc], acc1, 0, 0, 0);
    }

    // layer 3 epilogue: lane-local (col = own pair); w2 already includes scale
    float s = 0.0f;
    #pragma unroll
    for (int q = 0; q < 4; ++q) {
        const f32x4 u0 = *(const f32x4*)&w2sh[(q << 3) + (hi << 2)];
        const f32x4 u1 = *(const f32x4*)&w2sh[32 + (q << 3) + (hi << 2)];
        #pragma unroll
        for (int e = 0; e < 4; ++e) {
            s = fmaf(tanh_pre(acc0[(q << 2) + e]), u0[e], s);
            s = fmaf(tanh_pre(acc1[(q << 2) + e]), u1[e], s);
        }
    }
    if (diag) s = 0.0f;
    float partial = s + cusp;

    #pragma unroll
    for (int off = 32; off; off >>= 1) partial += __shfl_down(partial, off);
    if (lane == 0)
        atomicAdd(&accum[(((bidx << 2) + wv) & 63) << 4], partial);
}

__global__ __launch_bounds__(64) void final_kernel(const float* __restrict__ accum,
                                                   float* __restrict__ out)
{
    const int lane = threadIdx.x;
    float v = accum[lane << 4];
    #pragma unroll
    for (int off = 32; off; off >>= 1) v += __shfl_down(v, off);
    if (lane == 0) {
        const float J0 = accum[1024];
        const float J1 = accum[1025];
        const float sign = (J1 > 0.0f) ? 1.0f : ((J1 < 0.0f) ? -1.0f : 0.0f);
        out[0] = sign;
        out[1] = v + J0 + logf(fabsf(J1));
    }
}

extern "C" void kernel_launch(void* const* d_in, const int* in_sizes, int n_in,
                              void* d_out, int out_size, void* d_ws, size_t ws_size,
                              hipStream_t stream) {
    const float* electrons  = (const float*)d_in[0];
    const float* embeddings = (const float*)d_in[1];
    const float* A_same     = (const float*)d_in[2];
    const float* A_diff     = (const float*)d_in[3];
    const float* Ws0_same   = (const float*)d_in[4];
    const float* bs0_same   = (const float*)d_in[5];
    const float* Ws1_same   = (const float*)d_in[6];
    const float* bs1_same   = (const float*)d_in[7];
    const float* Ws2_same   = (const float*)d_in[8];
    const float* Ws0_diff   = (const float*)d_in[9];
    const float* bs0_diff   = (const float*)d_in[10];
    const float* bs1_diffW  = (const float*)d_in[11]; // Ws1_diff
    const float* bs1_diff   = (const float*)d_in[12];
    const float* Ws2_diff   = (const float*)d_in[13];
    const float* scale_same = (const float*)d_in[14];
    const float* scale_diff = (const float*)d_in[15];
    const float* We0        = (const float*)d_in[16];
    const float* be0        = (const float*)d_in[17];
    const float* We1        = (const float*)d_in[18];
    const float* be1        = (const float*)d_in[19];
    const float* We2        = (const float*)d_in[20];
    const float* be2        = (const float*)d_in[21];
    const float* mlp_scale  = (const float*)d_in[22];
    const float* log_bias   = (const float*)d_in[23];

    float* out = (float*)d_out;
    float* wsf = (float*)d_ws;

    hipLaunchKernelGGL(prep_kernel, dim3(17), dim3(256), 0, stream,
        Ws0_same, bs0_same, Ws1_same, bs1_same, Ws2_same,
        Ws0_diff, bs0_diff, bs1_diffW, bs1_diff, Ws2_diff,
        A_same, A_diff, scale_same, scale_diff, wsf);

    hipLaunchKernelGGL(pair_kernel, dim3(8448), dim3(256), 0, stream,
        electrons, wsf, wsf,
        embeddings, We0, be0, We1, be1, We2, be2, mlp_scale, log_bias);

    hipLaunchKernelGGL(final_kernel, dim3(1), dim3(64), 0, stream, wsf, out);
}

// Round 5
// 77.783 us; speedup vs baseline: 3.2336x; 1.0472x over previous
//
#include <hip/hip_runtime.h>
#include <hip/hip_bf16.h>

#define NEL 1024
#define NUP 512
#define DEMB 256
#define WID 64

typedef __attribute__((ext_vector_type(8))) short bf16x8;
typedef __attribute__((ext_vector_type(4))) float f32x4;
typedef __attribute__((ext_vector_type(16))) float f32x16;

#define CTANH 2.8853900817779268f   // 2*log2(e): tanh(a)=1-2/(exp2(CTANH*a)+1)
#define LOG2E 1.4426950408889634f
#define LN2   0.6931471805599453f

// ws float layout:
//  [0..1023]    : 64 spread accumulation buckets (stride 16)
//  [1024,1025]  : J0, J1
//  [2048+s*1024]: per-set: w0t[256] (W0^T*CTANH), +256 b0p[64]*CTANH,
//                 +320 b1p[64]*CTANH, +384 w2p[64]*scale, +448 {A, log2e/F}
//  float idx 4096 onward, as shorts: w1t_s[4608], w1t_d[4608]  ([n][72] bf16, *CTANH)

__device__ __forceinline__ float tanh_pre(float y) {
    // y = CTANH * a ; returns tanh(a). Saturates correctly, NaN-free for finite y.
    float e = __builtin_amdgcn_exp2f(y);
    return fmaf(-2.0f, __builtin_amdgcn_rcpf(e + 1.0f), 1.0f);
}

__device__ __forceinline__ short f2bf(float x) {
    unsigned u = __builtin_bit_cast(unsigned, x);
    u += 0x7FFFu + ((u >> 16) & 1u);
    return (short)(u >> 16);
}

__device__ __forceinline__ float softplus_f(float x) {
    return fmaxf(x, 0.0f) + __logf(1.0f + __expf(-fabsf(x)));
}

__global__ __launch_bounds__(256) void prep_kernel(
    const float* __restrict__ W0s, const float* __restrict__ b0s,
    const float* __restrict__ W1s, const float* __restrict__ b1s, const float* __restrict__ W2s,
    const float* __restrict__ W0d, const float* __restrict__ b0d,
    const float* __restrict__ W1d, const float* __restrict__ b1d, const float* __restrict__ W2d,
    const float* __restrict__ As, const float* __restrict__ Ad,
    const float* __restrict__ ss, const float* __restrict__ sd,
    float* __restrict__ wsf)
{
    short* w1ws = (short*)(wsf + 4096);
    const int b = blockIdx.x, tid = threadIdx.x;
    if (b < 16) {
        const int s = b >> 3, c = b & 7;
        const float* W1 = s ? W1d : W1s;
        #pragma unroll
        for (int it = 0; it < 2; ++it) {
            const int local = (c << 9) + (it << 8) + tid;   // 512 entries per block
            const int n = local >> 6, k = local & 63;
            w1ws[s * 4608 + n * 72 + k] = f2bf(CTANH * W1[k * 64 + n]);
        }
    } else {
        for (int idx = tid; idx < 1026; idx += 256) wsf[idx] = 0.0f;
        #pragma unroll
        for (int s = 0; s < 2; ++s) {
            const float* W0 = s ? W0d : W0s;
            const float* b0 = s ? b0d : b0s;
            const float* b1 = s ? b1d : b1s;
            const float* w2 = s ? W2d : W2s;
            const float scl = (s ? sd : ss)[0];
            const int base = 2048 + s * 1024;
            { const int k = tid >> 6, n = tid & 63; wsf[base + n * 4 + k] = CTANH * W0[tid]; }
            if (tid < 64) {
                wsf[base + 256 + tid] = CTANH * b0[tid];
                wsf[base + 320 + tid] = CTANH * b1[tid];
                wsf[base + 384 + tid] = scl * w2[tid];
            }
            if (tid == 0) {
                const float A = softplus_f((s ? Ad : As)[0]);
                wsf[base + 448] = A;
                wsf[base + 449] = LOG2E * __builtin_amdgcn_rsqf(2.0f * A);  // log2e/F
            }
        }
    }
}

// Blocks [0,8192): 128 pairs each (wave = 32 pairs, MFMA 32x32x16).
// Blocks [8192,8448): embedding MLP, 4 rows per block.
// launch_bounds(256, 8): force VGPR<=64 — crossing 64 halves waves/SIMD (m69).
__global__ __launch_bounds__(256, 8) void pair_kernel(
    const float* __restrict__ electrons,
    const float* __restrict__ wsf,
    float* __restrict__ accum,
    const float* __restrict__ emb,
    const float* __restrict__ We0, const float* __restrict__ be0,
    const float* __restrict__ We1, const float* __restrict__ be1,
    const float* __restrict__ We2, const float* __restrict__ be2,
    const float* __restrict__ mlp_scale, const float* __restrict__ log_bias)
{
    __shared__ __align__(16) char smem[11264];
    const int tid = threadIdx.x, bidx = blockIdx.x;
    const int lane = tid & 63, wv = tid >> 6;

    if (bidx >= 8192) {
        // ---------------- embedding path ----------------
        float* xs  = (float*)smem;          // [4][256]
        float* h0s = (float*)(smem + 4096); // [4][64]
        const int row = ((bidx - 8192) << 2) + wv;

        for (int k = lane; k < DEMB; k += 64) xs[(wv << 8) + k] = emb[row * DEMB + k];
        __syncthreads();

        float a0 = 0, a1 = 0;
        #pragma unroll 2
        for (int k = 0; k < DEMB; k += 2) {
            a0 = fmaf(xs[(wv << 8) + k],     We0[(k)     * WID + lane], a0);
            a1 = fmaf(xs[(wv << 8) + k + 1], We0[(k + 1) * WID + lane], a1);
        }
        h0s[(wv << 6) + lane] = tanh_pre(CTANH * (a0 + a1 + be0[lane]));
        __syncthreads();

        float c0 = 0, c1 = 0;
        #pragma unroll 2
        for (int k = 0; k < WID; k += 2) {
            c0 = fmaf(h0s[(wv << 6) + k],     We1[(k)     * WID + lane], c0);
            c1 = fmaf(h0s[(wv << 6) + k + 1], We1[(k + 1) * WID + lane], c1);
        }
        const float h1 = tanh_pre(CTANH * (c0 + c1 + be1[lane]));

        float p0 = h1 * We2[2 * lane], p1 = h1 * We2[2 * lane + 1];
        #pragma unroll
        for (int off = 32; off; off >>= 1) {
            p0 += __shfl_down(p0, off);
            p1 += __shfl_down(p1, off);
        }
        if (lane == 0) {
            atomicAdd(&accum[1024], (p0 + be2[0]) * mlp_scale[0]);
            atomicAdd(&accum[1025], (p1 + be2[1]) * mlp_scale[1] + log_bias[0]);
        }
        return;
    }

    // ---------------- pair path ----------------
    short* w1t  = (short*)smem;            // [64][72] bf16, prescaled
    float* w0t  = (float*)(smem + 9216);   // [64][4]  f32, prescaled
    float* b0sh = (float*)(smem + 10240);  // [64]
    float* b1sh = (float*)(smem + 10496);  // [64]
    float* w2sh = (float*)(smem + 10752);  // [64] (pre-multiplied by scale)
    float* wsum = (float*)(smem + 11008);  // [4]

    const int i  = bidx >> 3;
    const int jb = (bidx & 7) << 7;        // 128 j per block (spin-uniform)
    const int sset = ((i < NUP) == (jb < NUP)) ? 0 : 1;
    const float* wbase = wsf + 2048 + sset * 1024;
    const short* w1g   = (const short*)(wsf + 4096) + sset * 4608;

    {
        const float4* src = (const float4*)w1g;
        float4* dst = (float4*)w1t;
        for (int idx = tid; idx < 576; idx += 256) dst[idx] = src[idx];
        if (tid < 64) {
            ((float4*)w0t)[tid] = ((const float4*)wbase)[tid];
            b0sh[tid] = wbase[256 + tid];
            b1sh[tid] = wbase[320 + tid];
            w2sh[tid] = wbase[384 + tid];
        }
    }
    const float A     = wbase[448];
    const float invF2 = wbase[449];

    const int hi = lane >> 5, p32 = lane & 31;
    const int j = jb + (wv << 5) + p32;
    const bool diag = (j == i);

    // features (loads don't depend on LDS; issue before the barrier)
    const float eix = electrons[3 * i], eiy = electrons[3 * i + 1], eiz = electrons[3 * i + 2];
    float dx = eix - electrons[3 * j];
    float dy = eiy - electrons[3 * j + 1];
    float dz = eiz - electrons[3 * j + 2];
    if (diag) { dx = 0.0f; dy = 0.0f; dz = 0.0f; }
    float r2 = fmaf(dx, dx, fmaf(dy, dy, dz * dz));
    if (diag) r2 = 1.0f;
    const float rr    = __builtin_amdgcn_sqrtf(r2);
    const float inv_r = __builtin_amdgcn_rcpf(rr);
    const float l1p   = __builtin_amdgcn_logf(1.0f + rr) * LN2;
    const float gf    = l1p * inv_r;
    const float f0 = dx * gf, f1 = dy * gf, f2v = dz * gf;
    const float f3 = diag ? 0.0f : l1p;
    const float cusp = (hi == 0 && !diag)
        ? A * (__builtin_amdgcn_exp2f(-rr * invF2) - 1.0f) * inv_r : 0.0f;

    __syncthreads();

    // layer 1 (VALU) straight into B-fragment layout:
    // lane owns pair p32; k-elem e of chunk kc = neuron n = 16*kc + 8*hi + e
    bf16x8 afr[4];
    #pragma unroll
    for (int kc = 0; kc < 4; ++kc) {
        #pragma unroll
        for (int e = 0; e < 8; ++e) {
            const int n = (kc << 4) + (hi << 3) + e;
            f32x4 w = *(const f32x4*)&w0t[n << 2];
            float y = fmaf(f3, w[3], fmaf(f2v, w[2], fmaf(f1, w[1], fmaf(f0, w[0], b0sh[n]))));
            afr[kc][e] = __bfloat16_as_ushort(__float2bfloat16(tanh_pre(y)));
        }
    }

    // layer 2 (MFMA 32x32x16), C preloaded with prescaled b1 via broadcast b128 reads
    f32x16 acc0, acc1;
    #pragma unroll
    for (int q = 0; q < 4; ++q) {
        const f32x4 v0 = *(const f32x4*)&b1sh[(q << 3) + (hi << 2)];
        const f32x4 v1 = *(const f32x4*)&b1sh[32 + (q << 3) + (hi << 2)];
        #pragma unroll
        for (int e = 0; e < 4; ++e) { acc0[(q << 2) + e] = v0[e]; acc1[(q << 2) + e] = v1[e]; }
    }
    const short* w1r0 = &w1t[p32 * 72 + (hi << 3)];
    const short* w1r1 = &w1t[(32 + p32) * 72 + (hi << 3)];
    #pragma unroll
    for (int kc = 0; kc < 4; ++kc) {
        bf16x8 wa0 = *(const bf16x8*)(w1r0 + (kc << 4));
        bf16x8 wa1 = *(const bf16x8*)(w1r1 + (kc << 4));
        acc0 = __builtin_amdgcn_mfma_f32_32x32x16_bf16(wa0, afr[kc], acc0, 0, 0, 0);
        acc1 = __builtin_amdgcn_mfma_f32_32x32x16_bf16(wa1, afr[kc], acc1, 0, 0, 0);
    }

    // layer 3 epilogue: lane-local (col = own pair); w2 already includes scale
    float s = 0.0f;
    #pragma unroll
    for (int q = 0; q < 4; ++q) {
        const f32x4 u0 = *(const f32x4*)&w2sh[(q << 3) + (hi << 2)];
        const f32x4 u1 = *(const f32x4*)&w2sh[32 + (q << 3) + (hi << 2)];
        #pragma unroll
        for (int e = 0; e < 4; ++e) {
            s = fmaf(tanh_pre(acc0[(q << 2) + e]), u0[e], s);
            s = fmaf(tanh_pre(acc1[(q << 2) + e]), u1[e], s);
        }
    }
    if (diag) s = 0.0f;
    float partial = s + cusp;

    #pragma unroll
    for (int off = 32; off; off >>= 1) partial += __shfl_down(partial, off);
    if (lane == 0) wsum[wv] = partial;
    __syncthreads();
    if (tid == 0)
        atomicAdd(&accum[(bidx & 63) << 4], wsum[0] + wsum[1] + wsum[2] + wsum[3]);
}

__global__ __launch_bounds__(64) void final_kernel(const float* __restrict__ accum,
                                                   float* __restrict__ out)
{
    const int lane = threadIdx.x;
    float v = accum[lane << 4];
    #pragma unroll
    for (int off = 32; off; off >>= 1) v += __shfl_down(v, off);
    if (lane == 0) {
        const float J0 = accum[1024];
        const float J1 = accum[1025];
        const float sign = (J1 > 0.0f) ? 1.0f : ((J1 < 0.0f) ? -1.0f : 0.0f);
        out[0] = sign;
        out[1] = v + J0 + logf(fabsf(J1));
    }
}

extern "C" void kernel_launch(void* const* d_in, const int* in_sizes, int n_in,
                              void* d_out, int out_size, void* d_ws, size_t ws_size,
                              hipStream_t stream) {
    const float* electrons  = (const float*)d_in[0];
    const float* embeddings = (const float*)d_in[1];
    const float* A_same     = (const float*)d_in[2];
    const float* A_diff     = (const float*)d_in[3];
    const float* Ws0_same   = (const float*)d_in[4];
    const float* bs0_same   = (const float*)d_in[5];
    const float* Ws1_same   = (const float*)d_in[6];
    const float* bs1_same   = (const float*)d_in[7];
    const float* Ws2_same   = (const float*)d_in[8];
    const float* Ws0_diff   = (const float*)d_in[9];
    const float* bs0_diff   = (const float*)d_in[10];
    const float* Ws1_diff   = (const float*)d_in[11];
    const float* bs1_diff   = (const float*)d_in[12];
    const float* Ws2_diff   = (const float*)d_in[13];
    const float* scale_same = (const float*)d_in[14];
    const float* scale_diff = (const float*)d_in[15];
    const float* We0        = (const float*)d_in[16];
    const float* be0        = (const float*)d_in[17];
    const float* We1        = (const float*)d_in[18];
    const float* be1        = (const float*)d_in[19];
    const float* We2        = (const float*)d_in[20];
    const float* be2        = (const float*)d_in[21];
    const float* mlp_scale  = (const float*)d_in[22];
    const float* log_bias   = (const float*)d_in[23];

    float* out = (float*)d_out;
    float* wsf = (float*)d_ws;

    hipLaunchKernelGGL(prep_kernel, dim3(17), dim3(256), 0, stream,
        Ws0_same, bs0_same, Ws1_same, bs1_same, Ws2_same,
        Ws0_diff, bs0_diff, Ws1_diff, bs1_diff, Ws2_diff,
        A_same, A_diff, scale_same, scale_diff, wsf);

    hipLaunchKernelGGL(pair_kernel, dim3(8448), dim3(256), 0, stream,
        electrons, wsf, wsf,
        embeddings, We0, be0, We1, be1, We2, be2, mlp_scale, log_bias);

    hipLaunchKernelGGL(final_kernel, dim3(1), dim3(64), 0, stream, wsf, out);
}